// Round 1
// 405.787 us; speedup vs baseline: 8.0975x; 8.0975x over previous
//
#include <hip/hip_runtime.h>
#include <stdint.h>

#define DD 128
#define NJ 25000
#define NI 12500

__device__ __forceinline__ uint32_t rotl32(uint32_t v, int n) {
  return (v << n) | (v >> (32 - n));
}

// JAX threefry2x32, key=(0,1). Core KAT-verified vs Random123.
__device__ __forceinline__ void threefry_0_1(uint32_t& x0, uint32_t& x1) {
  const uint32_t ks0 = 0u, ks1 = 1u, ks2 = 0x1BD11BDBu;
  x0 += ks0; x1 += ks1;
#define TF_R4(a,b,c,d)                                  \
  x0 += x1; x1 = rotl32(x1,(a)); x1 ^= x0;              \
  x0 += x1; x1 = rotl32(x1,(b)); x1 ^= x0;              \
  x0 += x1; x1 = rotl32(x1,(c)); x1 ^= x0;              \
  x0 += x1; x1 = rotl32(x1,(d)); x1 ^= x0;
  TF_R4(13,15,26,6)   x0 += ks1; x1 += ks2 + 1u;
  TF_R4(17,29,16,24)  x0 += ks2; x1 += ks0 + 2u;
  TF_R4(13,15,26,6)   x0 += ks0; x1 += ks1 + 3u;
  TF_R4(17,29,16,24)  x0 += ks1; x1 += ks2 + 4u;
  TF_R4(13,15,26,6)   x0 += ks2; x1 += ks0 + 5u;
#undef TF_R4
}

// MASK IDENTIFIED (R16 sweep, unique match v5): partitionable threefry,
// ctr = (0, f), 32-bit draw = o0 ^ o1; keep <=> bit31(o0 ^ o1) == 0.
__device__ __forceinline__ bool dropout_keep(uint32_t f) {
  uint32_t x0 = 0u, x1 = f;
  threefry_0_1(x0, x1);
  return ((x0 ^ x1) >> 31) == 0u;
}

// int64-as-int32-pairs detection (odd words all zero for values < 2^31).
__global__ void detect_i64(const int* __restrict__ w, int* __restrict__ flag) {
  if (threadIdx.x == 0 && blockIdx.x == 0) {
    int is64 = 1;
    for (int e = 0; e < 16; ++e)
      if (w[2 * e + 1] != 0) is64 = 0;
    *flag = is64;
  }
}

// WTp[(k>>2)*512 + c*4 + (k&3)] = Wcat[c][k]; Wcat = [W_l | W_r] along k.
__global__ void prep_wt(const float* __restrict__ Wl,
                        const float* __restrict__ Wr,
                        float* __restrict__ WTp) {
  int idx = blockIdx.x * blockDim.x + threadIdx.x;  // idx = c*256 + k
  if (idx >= DD * 256) return;
  int c = idx >> 8;
  int k = idx & 255;
  float v = (k < DD) ? Wl[c * DD + k] : Wr[c * DD + (k - DD)];
  WTp[(k >> 2) * (DD * 4) + c * 4 + (k & 3)] = v;
}

// ---- CSR build: hist -> exclusive scan -> fill (counting sort by dst) ----

__global__ void hist_kernel(const int* __restrict__ adj, int* __restrict__ cnt,
                            const int* __restrict__ flagIdx, int nE,
                            int dstLimit) {
  int e = blockIdx.x * blockDim.x + threadIdx.x;
  if (e >= nE) return;
  int d = (*flagIdx) ? adj[2 * nE + 2 * e] : adj[nE + e];
  if (d < dstLimit) atomicAdd(&cnt[d], 1);
}

// Single-block in-place exclusive scan (segmented: read-before-write per seg).
__global__ void scan_kernel(int* __restrict__ a, int n) {
  __shared__ int part[256];
  const int t = threadIdx.x;
  const int per = (n + 255) / 256;
  int lo = t * per;
  int hi = lo + per;
  if (hi > n) hi = n;
  int sum = 0;
  for (int i = lo; i < hi; ++i) sum += a[i];
  part[t] = sum;
  __syncthreads();
  for (int ofs = 1; ofs < 256; ofs <<= 1) {
    int v = (t >= ofs) ? part[t - ofs] : 0;
    __syncthreads();
    part[t] += v;
    __syncthreads();
  }
  int run = (t == 0) ? 0 : part[t - 1];
  for (int i = lo; i < hi; ++i) {
    int v = a[i];
    a[i] = run;
    run += v;
  }
}

// fill: cur[] holds exclusive starts on entry; inclusive ENDS on exit
// (cur[d] == off[d+1]); gather derives start = (d ? cur[d-1] : 0).
__global__ void fill_kernel(const int* __restrict__ adj, int* __restrict__ cur,
                            int* __restrict__ csr,
                            const int* __restrict__ flagIdx, int nE,
                            int dstLimit) {
  int e = blockIdx.x * blockDim.x + threadIdx.x;
  if (e >= nE) return;
  int s, d;
  if (*flagIdx) {
    s = adj[2 * e];
    d = adj[2 * nE + 2 * e];
  } else {
    s = adj[e];
    d = adj[nE + e];
  }
  if (d < dstLimit) {
    int pos = atomicAdd(&cur[d], 1);
    csr[pos] = s;
  }
}

// Fused gather + dense: out[r][c] = bias[c] + sum_k [mean_nb(xsrc) || xin][k] * Wcat[c][k].
// 8 rows/block; aggregation is done in registers from the CSR (no atomics,
// no materialized agg). LAYER==1: relu + dropout epilogue.
template <int LAYER>
__global__ __launch_bounds__(256) void dense_kernel(
    const float* __restrict__ xsrc, const int* __restrict__ csr,
    const int* __restrict__ offEnd, const float* __restrict__ xin,
    const float* __restrict__ WTp, const float* __restrict__ bias,
    float* __restrict__ out, int M) {
  __shared__ float As[8 * 256];
  const int tid = threadIdx.x;
  const int c = tid & 127;
  const int team = tid >> 7;  // 2 teams of 128 threads; 4 rows each
  const int rowBase = blockIdx.x * 8;

#pragma unroll
  for (int rr = 0; rr < 4; ++rr) {
    int r = team * 4 + rr;
    int rg = rowBase + r;
    if (rg >= M) rg = M - 1;  // clamped read; stores guarded below
    const int end = offEnd[rg];
    const int start = (rg == 0) ? 0 : offEnd[rg - 1];
    float acc0 = 0.f, acc1 = 0.f;
    int e = start;
    for (; e + 1 < end; e += 2) {
      int s0 = csr[e];
      int s1 = csr[e + 1];
      acc0 += xsrc[(size_t)s0 * DD + c];
      acc1 += xsrc[(size_t)s1 * DD + c];
    }
    if (e < end) acc0 += xsrc[(size_t)csr[e] * DD + c];
    float rdeg = 1.0f / fmaxf((float)(end - start), 1.0f);
    As[r * 256 + c] = (acc0 + acc1) * rdeg;
    As[r * 256 + DD + c] = xin[(size_t)rg * DD + c];
  }
  __syncthreads();

  float acc[4] = {0.f, 0.f, 0.f, 0.f};
  const int r0 = team * 4;
#pragma unroll 8
  for (int k0 = 0; k0 < 256; k0 += 4) {
    float4 w = *(const float4*)(WTp + (k0 >> 2) * (DD * 4) + c * 4);
#pragma unroll
    for (int r = 0; r < 4; ++r) {
      float4 a = *(const float4*)(As + (r0 + r) * 256 + k0);
      acc[r] += a.x * w.x + a.y * w.y + a.z * w.z + a.w * w.w;
    }
  }

  float b = bias[c];
#pragma unroll
  for (int r = 0; r < 4; ++r) {
    int rg = rowBase + r0 + r;
    if (rg >= M) continue;
    float v = acc[r] + b;
    if (LAYER == 1) {
      v = fmaxf(v, 0.0f);
      uint32_t f = (uint32_t)rg * DD + (uint32_t)c;
      v = dropout_keep(f) ? v * 2.0f : 0.0f;
    }
    out[(size_t)rg * DD + c] = v;
  }
}

extern "C" void kernel_launch(void* const* d_in, const int* in_sizes, int n_in,
                              void* d_out, int out_size, void* d_ws, size_t ws_size,
                              hipStream_t stream) {
  const float* feat = (const float*)d_in[0];   // fp32 (R4 NaN proof)
  const int* t_adj = (const int*)d_in[1];
  const int* n_adj = (const int*)d_in[2];
  const float* W1l = (const float*)d_in[5];
  const float* b1 = (const float*)d_in[6];
  const float* W1r = (const float*)d_in[7];
  const float* W2l = (const float*)d_in[8];
  const float* b2 = (const float*)d_in[9];
  const float* W2r = (const float*)d_in[10];

  const int E1 = in_sizes[1] / 2;
  const int E2 = in_sizes[2] / 2;

  // Workspace ~16 MB (was 19.6): agg/deg arrays gone, CSR added.
  float* ws = (float*)d_ws;
  float* x1 = ws;                       // 3,200,000 f
  float* WT1 = x1 + 3200000;            //    32,768 f
  float* WT2 = WT1 + 32768;             //    32,768 f
  int* off1 = (int*)(WT2 + 32768);      //    NJ
  int* off2 = off1 + NJ;                //    NI
  int* csr1 = off2 + NI;                //    E1 (max)
  int* csr2 = csr1 + E1;                //    E2 (max)
  int* flagIdx = csr2 + E2;             //    1

  hipMemsetAsync(off1, 0, (size_t)(NJ + NI) * sizeof(int), stream);

  detect_i64<<<1, 64, 0, stream>>>(t_adj, flagIdx);

  prep_wt<<<(DD * 256 + 255) / 256, 256, 0, stream>>>(W1l, W1r, WT1);
  prep_wt<<<(DD * 256 + 255) / 256, 256, 0, stream>>>(W2l, W2r, WT2);

  // Layer 1: CSR build + fused gather/dense
  hist_kernel<<<(E1 + 255) / 256, 256, 0, stream>>>(t_adj, off1, flagIdx, E1, NJ);
  scan_kernel<<<1, 256, 0, stream>>>(off1, NJ);
  fill_kernel<<<(E1 + 255) / 256, 256, 0, stream>>>(t_adj, off1, csr1, flagIdx,
                                                    E1, NJ);
  dense_kernel<1><<<(NJ + 7) / 8, 256, 0, stream>>>(feat, csr1, off1, feat, WT1,
                                                    b1, x1, NJ);

  // Layer 2
  hist_kernel<<<(E2 + 255) / 256, 256, 0, stream>>>(n_adj, off2, flagIdx, E2, NI);
  scan_kernel<<<1, 256, 0, stream>>>(off2, NI);
  fill_kernel<<<(E2 + 255) / 256, 256, 0, stream>>>(n_adj, off2, csr2, flagIdx,
                                                    E2, NI);
  dense_kernel<2><<<(NI + 7) / 8, 256, 0, stream>>>(x1, csr2, off2, x1, WT2, b2,
                                                    (float*)d_out, NI);
}

// Round 2
// 296.415 us; speedup vs baseline: 11.0853x; 1.3690x over previous
//
#include <hip/hip_runtime.h>
#include <stdint.h>

#define DD 128
#define NJ 25000
#define NI 12500

__device__ __forceinline__ uint32_t rotl32(uint32_t v, int n) {
  return (v << n) | (v >> (32 - n));
}

// JAX threefry2x32, key=(0,1). Core KAT-verified vs Random123.
__device__ __forceinline__ void threefry_0_1(uint32_t& x0, uint32_t& x1) {
  const uint32_t ks0 = 0u, ks1 = 1u, ks2 = 0x1BD11BDBu;
  x0 += ks0; x1 += ks1;
#define TF_R4(a,b,c,d)                                  \
  x0 += x1; x1 = rotl32(x1,(a)); x1 ^= x0;              \
  x0 += x1; x1 = rotl32(x1,(b)); x1 ^= x0;              \
  x0 += x1; x1 = rotl32(x1,(c)); x1 ^= x0;              \
  x0 += x1; x1 = rotl32(x1,(d)); x1 ^= x0;
  TF_R4(13,15,26,6)   x0 += ks1; x1 += ks2 + 1u;
  TF_R4(17,29,16,24)  x0 += ks2; x1 += ks0 + 2u;
  TF_R4(13,15,26,6)   x0 += ks0; x1 += ks1 + 3u;
  TF_R4(17,29,16,24)  x0 += ks1; x1 += ks2 + 4u;
  TF_R4(13,15,26,6)   x0 += ks2; x1 += ks0 + 5u;
#undef TF_R4
}

// MASK IDENTIFIED (R16 sweep, unique match v5): partitionable threefry,
// ctr = (0, f), 32-bit draw = o0 ^ o1; keep <=> bit31(o0 ^ o1) == 0.
__device__ __forceinline__ bool dropout_keep(uint32_t f) {
  uint32_t x0 = 0u, x1 = f;
  threefry_0_1(x0, x1);
  return ((x0 ^ x1) >> 31) == 0u;
}

__device__ __forceinline__ float4 ld4(const float* p) {
  return *(const float4*)p;
}

// int64-as-int32-pairs detection (odd words all zero for values < 2^31).
__global__ void detect_i64(const int* __restrict__ w, int* __restrict__ flag) {
  if (threadIdx.x == 0 && blockIdx.x == 0) {
    int is64 = 1;
    for (int e = 0; e < 16; ++e)
      if (w[2 * e + 1] != 0) is64 = 0;
    *flag = is64;
  }
}

// Both weight preps in one dispatch.
// WTp[(k>>2)*512 + c*4 + (k&3)] = Wcat[c][k]; Wcat = [W_l | W_r] along k.
__global__ void prep_wt2(const float* __restrict__ Wl1,
                         const float* __restrict__ Wr1,
                         float* __restrict__ WT1,
                         const float* __restrict__ Wl2,
                         const float* __restrict__ Wr2,
                         float* __restrict__ WT2) {
  int t = blockIdx.x * blockDim.x + threadIdx.x;
  int which = t >= DD * 256;
  int idx = which ? t - DD * 256 : t;
  if (idx >= DD * 256) return;
  const float* Wl = which ? Wl2 : Wl1;
  const float* Wr = which ? Wr2 : Wr1;
  float* WTp = which ? WT2 : WT1;
  int c = idx >> 8;
  int k = idx & 255;
  float v = (k < DD) ? Wl[c * DD + k] : Wr[c * DD + (k - DD)];
  WTp[(k >> 2) * (DD * 4) + c * 4 + (k & 3)] = v;
}

// ---- CSR build (both graphs): hist -> scan -> fill ----

__global__ void hist_both(const int* __restrict__ adj1,
                          const int* __restrict__ adj2,
                          int* __restrict__ cnt1, int* __restrict__ cnt2,
                          const int* __restrict__ flagIdx, int nE1, int nE2) {
  int t = blockIdx.x * blockDim.x + threadIdx.x;
  int f = *flagIdx;
  if (t < nE1) {
    int d = f ? adj1[2 * nE1 + 2 * t] : adj1[nE1 + t];
    if (d < NJ) atomicAdd(&cnt1[d], 1);
  } else if (t < nE1 + nE2) {
    int e = t - nE1;
    int d = f ? adj2[2 * nE2 + 2 * e] : adj2[nE2 + e];
    if (d < NI) atomicAdd(&cnt2[d], 1);
  }
}

// In-place exclusive scan; block 0 -> (a1,n1), block 1 -> (a2,n2).
__global__ void scan2(int* __restrict__ a1, int n1, int* __restrict__ a2,
                      int n2) {
  __shared__ int part[256];
  int* a = blockIdx.x ? a2 : a1;
  const int n = blockIdx.x ? n2 : n1;
  const int t = threadIdx.x;
  const int per = (n + 255) / 256;
  int lo = t * per;
  int hi = lo + per;
  if (hi > n) hi = n;
  int sum = 0;
  for (int i = lo; i < hi; ++i) sum += a[i];
  part[t] = sum;
  __syncthreads();
  for (int ofs = 1; ofs < 256; ofs <<= 1) {
    int v = (t >= ofs) ? part[t - ofs] : 0;
    __syncthreads();
    part[t] += v;
    __syncthreads();
  }
  int run = (t == 0) ? 0 : part[t - 1];
  for (int i = lo; i < hi; ++i) {
    int v = a[i];
    a[i] = run;
    run += v;
  }
}

// fill: cur[] holds exclusive starts on entry; inclusive ENDS on exit
// (cur[d] == off[d+1]); gather derives start = (d ? cur[d-1] : 0).
__global__ void fill_both(const int* __restrict__ adj1,
                          const int* __restrict__ adj2,
                          int* __restrict__ cur1, int* __restrict__ cur2,
                          int* __restrict__ csr1, int* __restrict__ csr2,
                          const int* __restrict__ flagIdx, int nE1, int nE2) {
  int t = blockIdx.x * blockDim.x + threadIdx.x;
  int f = *flagIdx;
  if (t < nE1) {
    int s, d;
    if (f) {
      s = adj1[2 * t];
      d = adj1[2 * nE1 + 2 * t];
    } else {
      s = adj1[t];
      d = adj1[nE1 + t];
    }
    if (d < NJ) csr1[atomicAdd(&cur1[d], 1)] = s;
  } else if (t < nE1 + nE2) {
    int e = t - nE1;
    int s, d;
    if (f) {
      s = adj2[2 * e];
      d = adj2[2 * nE2 + 2 * e];
    } else {
      s = adj2[e];
      d = adj2[nE2 + e];
    }
    if (d < NI) csr2[atomicAdd(&cur2[d], 1)] = s;
  }
}

// Fused gather + dense. Gather: 8 teams x 32 lanes, one row per team, each
// lane owns 16 B (float4) of the row; 4-way unrolled accumulators for MLP.
// Dense: out[r][c] = bias[c] + sum_k [mean_nb || xin][k] * Wcat[c][k].
// LAYER==1: relu + dropout epilogue.
template <int LAYER>
__global__ __launch_bounds__(256) void dense_kernel(
    const float* __restrict__ xsrc, const int* __restrict__ csr,
    const int* __restrict__ offEnd, const float* __restrict__ xin,
    const float* __restrict__ WTp, const float* __restrict__ bias,
    float* __restrict__ out, int M) {
  __shared__ float As[8 * 256];
  const int tid = threadIdx.x;
  const int rowBase = blockIdx.x * 8;

  // ---- gather phase ----
  {
    const int trow = tid >> 5;       // 0..7: row within block
    const int l4 = (tid & 31) * 4;   // float4 slot within row
    int rg = rowBase + trow;
    if (rg >= M) rg = M - 1;  // clamped read; stores guarded below
    const int end = offEnd[rg];
    const int start = (rg == 0) ? 0 : offEnd[rg - 1];
    float4 a0 = {0.f, 0.f, 0.f, 0.f}, a1 = a0, a2 = a0, a3 = a0;
    int e = start;
    for (; e + 3 < end; e += 4) {
      int s0 = csr[e], s1 = csr[e + 1], s2 = csr[e + 2], s3 = csr[e + 3];
      float4 v0 = ld4(xsrc + (size_t)s0 * DD + l4);
      float4 v1 = ld4(xsrc + (size_t)s1 * DD + l4);
      float4 v2 = ld4(xsrc + (size_t)s2 * DD + l4);
      float4 v3 = ld4(xsrc + (size_t)s3 * DD + l4);
      a0.x += v0.x; a0.y += v0.y; a0.z += v0.z; a0.w += v0.w;
      a1.x += v1.x; a1.y += v1.y; a1.z += v1.z; a1.w += v1.w;
      a2.x += v2.x; a2.y += v2.y; a2.z += v2.z; a2.w += v2.w;
      a3.x += v3.x; a3.y += v3.y; a3.z += v3.z; a3.w += v3.w;
    }
    for (; e < end; ++e) {
      float4 v = ld4(xsrc + (size_t)csr[e] * DD + l4);
      a0.x += v.x; a0.y += v.y; a0.z += v.z; a0.w += v.w;
    }
    a0.x += a1.x + a2.x + a3.x;
    a0.y += a1.y + a2.y + a3.y;
    a0.z += a1.z + a2.z + a3.z;
    a0.w += a1.w + a2.w + a3.w;
    float rdeg = 1.0f / fmaxf((float)(end - start), 1.0f);
    a0.x *= rdeg; a0.y *= rdeg; a0.z *= rdeg; a0.w *= rdeg;
    *(float4*)(As + trow * 256 + l4) = a0;
    *(float4*)(As + trow * 256 + DD + l4) = ld4(xin + (size_t)rg * DD + l4);
  }
  __syncthreads();

  // ---- dense phase ----
  const int c = tid & 127;
  const int team = tid >> 7;
  float acc[4] = {0.f, 0.f, 0.f, 0.f};
  const int r0 = team * 4;
#pragma unroll 8
  for (int k0 = 0; k0 < 256; k0 += 4) {
    float4 w = *(const float4*)(WTp + (k0 >> 2) * (DD * 4) + c * 4);
#pragma unroll
    for (int r = 0; r < 4; ++r) {
      float4 a = *(const float4*)(As + (r0 + r) * 256 + k0);
      acc[r] += a.x * w.x + a.y * w.y + a.z * w.z + a.w * w.w;
    }
  }

  float b = bias[c];
#pragma unroll
  for (int r = 0; r < 4; ++r) {
    int rg = rowBase + r0 + r;
    if (rg >= M) continue;
    float v = acc[r] + b;
    if (LAYER == 1) {
      v = fmaxf(v, 0.0f);
      uint32_t f = (uint32_t)rg * DD + (uint32_t)c;
      v = dropout_keep(f) ? v * 2.0f : 0.0f;
    }
    out[(size_t)rg * DD + c] = v;
  }
}

extern "C" void kernel_launch(void* const* d_in, const int* in_sizes, int n_in,
                              void* d_out, int out_size, void* d_ws, size_t ws_size,
                              hipStream_t stream) {
  const float* feat = (const float*)d_in[0];   // fp32 (R4 NaN proof)
  const int* t_adj = (const int*)d_in[1];
  const int* n_adj = (const int*)d_in[2];
  const float* W1l = (const float*)d_in[5];
  const float* b1 = (const float*)d_in[6];
  const float* W1r = (const float*)d_in[7];
  const float* W2l = (const float*)d_in[8];
  const float* b2 = (const float*)d_in[9];
  const float* W2r = (const float*)d_in[10];

  const int E1 = in_sizes[1] / 2;
  const int E2 = in_sizes[2] / 2;

  // Workspace ~16 MB.
  float* ws = (float*)d_ws;
  float* x1 = ws;                       // 3,200,000 f
  float* WT1 = x1 + 3200000;            //    32,768 f
  float* WT2 = WT1 + 32768;             //    32,768 f
  int* off1 = (int*)(WT2 + 32768);      //    NJ
  int* off2 = off1 + NJ;                //    NI
  int* csr1 = off2 + NI;                //    E1 (max)
  int* csr2 = csr1 + E1;                //    E2 (max)
  int* flagIdx = csr2 + E2;             //    1

  hipMemsetAsync(off1, 0, (size_t)(NJ + NI) * sizeof(int), stream);

  detect_i64<<<1, 64, 0, stream>>>(t_adj, flagIdx);

  prep_wt2<<<(2 * DD * 256 + 255) / 256, 256, 0, stream>>>(W1l, W1r, WT1, W2l,
                                                           W2r, WT2);

  const int nTot = E1 + E2;
  hist_both<<<(nTot + 255) / 256, 256, 0, stream>>>(t_adj, n_adj, off1, off2,
                                                    flagIdx, E1, E2);
  scan2<<<2, 256, 0, stream>>>(off1, NJ, off2, NI);
  fill_both<<<(nTot + 255) / 256, 256, 0, stream>>>(
      t_adj, n_adj, off1, off2, csr1, csr2, flagIdx, E1, E2);

  dense_kernel<1><<<(NJ + 7) / 8, 256, 0, stream>>>(feat, csr1, off1, feat, WT1,
                                                    b1, x1, NJ);
  dense_kernel<2><<<(NI + 7) / 8, 256, 0, stream>>>(x1, csr2, off2, x1, WT2, b2,
                                                    (float*)d_out, NI);
}

// Round 3
// 295.950 us; speedup vs baseline: 11.1028x; 1.0016x over previous
//
#include <hip/hip_runtime.h>
#include <stdint.h>

#define DD 128
#define NJ 25000
#define NI 12500

__device__ __forceinline__ uint32_t rotl32(uint32_t v, int n) {
  return (v << n) | (v >> (32 - n));
}

// JAX threefry2x32, key=(0,1). Core KAT-verified vs Random123.
__device__ __forceinline__ void threefry_0_1(uint32_t& x0, uint32_t& x1) {
  const uint32_t ks0 = 0u, ks1 = 1u, ks2 = 0x1BD11BDBu;
  x0 += ks0; x1 += ks1;
#define TF_R4(a,b,c,d)                                  \
  x0 += x1; x1 = rotl32(x1,(a)); x1 ^= x0;              \
  x0 += x1; x1 = rotl32(x1,(b)); x1 ^= x0;              \
  x0 += x1; x1 = rotl32(x1,(c)); x1 ^= x0;              \
  x0 += x1; x1 = rotl32(x1,(d)); x1 ^= x0;
  TF_R4(13,15,26,6)   x0 += ks1; x1 += ks2 + 1u;
  TF_R4(17,29,16,24)  x0 += ks2; x1 += ks0 + 2u;
  TF_R4(13,15,26,6)   x0 += ks0; x1 += ks1 + 3u;
  TF_R4(17,29,16,24)  x0 += ks1; x1 += ks2 + 4u;
  TF_R4(13,15,26,6)   x0 += ks2; x1 += ks0 + 5u;
#undef TF_R4
}

// MASK IDENTIFIED (R16 sweep, unique match v5): partitionable threefry,
// ctr = (0, f), 32-bit draw = o0 ^ o1; keep <=> bit31(o0 ^ o1) == 0.
__device__ __forceinline__ bool dropout_keep(uint32_t f) {
  uint32_t x0 = 0u, x1 = f;
  threefry_0_1(x0, x1);
  return ((x0 ^ x1) >> 31) == 0u;
}

__device__ __forceinline__ float4 ld4(const float* p) {
  return *(const float4*)p;
}

// Fused setup (one dispatch):
//   blocks 0..255   : weight prep for BOTH layers
//   block  256      : int64-as-int32-pairs detect (odd words zero)
//   blocks 257..    : zero off1/off2 histogram arrays
// WTp[(k>>2)*512 + c*4 + (k&3)] = Wcat[c][k]; Wcat = [W_l | W_r] along k.
__global__ void setup_kernel(const float* __restrict__ Wl1,
                             const float* __restrict__ Wr1,
                             float* __restrict__ WT1,
                             const float* __restrict__ Wl2,
                             const float* __restrict__ Wr2,
                             float* __restrict__ WT2,
                             const int* __restrict__ adjw,
                             int* __restrict__ flag,
                             int* __restrict__ offZero, int nZero) {
  const int b = blockIdx.x;
  if (b < 256) {
    int t = b * 256 + threadIdx.x;  // 0..65535 covers both weight sets
    int which = t >= DD * 256;
    int idx = which ? t - DD * 256 : t;
    const float* Wl = which ? Wl2 : Wl1;
    const float* Wr = which ? Wr2 : Wr1;
    float* WTp = which ? WT2 : WT1;
    int c = idx >> 8;
    int k = idx & 255;
    float v = (k < DD) ? Wl[c * DD + k] : Wr[c * DD + (k - DD)];
    WTp[(k >> 2) * (DD * 4) + c * 4 + (k & 3)] = v;
  } else if (b == 256) {
    if (threadIdx.x == 0) {
      int is64 = 1;
      for (int e = 0; e < 16; ++e)
        if (adjw[2 * e + 1] != 0) is64 = 0;
      *flag = is64;
    }
  } else {
    int i = (b - 257) * 256 + threadIdx.x;
    if (i < nZero) offZero[i] = 0;
  }
}

// ---- CSR build (both graphs): hist -> scan -> fill ----

__global__ void hist_both(const int* __restrict__ adj1,
                          const int* __restrict__ adj2,
                          int* __restrict__ cnt1, int* __restrict__ cnt2,
                          const int* __restrict__ flagIdx, int nE1, int nE2) {
  int t = blockIdx.x * blockDim.x + threadIdx.x;
  int f = *flagIdx;
  if (t < nE1) {
    int d = f ? adj1[2 * nE1 + 2 * t] : adj1[nE1 + t];
    if (d < NJ) atomicAdd(&cnt1[d], 1);
  } else if (t < nE1 + nE2) {
    int e = t - nE1;
    int d = f ? adj2[2 * nE2 + 2 * e] : adj2[nE2 + e];
    if (d < NI) atomicAdd(&cnt2[d], 1);
  }
}

// In-place exclusive scan; block 0 -> (a1,n1), block 1 -> (a2,n2).
__global__ void scan2(int* __restrict__ a1, int n1, int* __restrict__ a2,
                      int n2) {
  __shared__ int part[256];
  int* a = blockIdx.x ? a2 : a1;
  const int n = blockIdx.x ? n2 : n1;
  const int t = threadIdx.x;
  const int per = (n + 255) / 256;
  int lo = t * per;
  int hi = lo + per;
  if (hi > n) hi = n;
  int sum = 0;
  for (int i = lo; i < hi; ++i) sum += a[i];
  part[t] = sum;
  __syncthreads();
  for (int ofs = 1; ofs < 256; ofs <<= 1) {
    int v = (t >= ofs) ? part[t - ofs] : 0;
    __syncthreads();
    part[t] += v;
    __syncthreads();
  }
  int run = (t == 0) ? 0 : part[t - 1];
  for (int i = lo; i < hi; ++i) {
    int v = a[i];
    a[i] = run;
    run += v;
  }
}

// fill: cur[] holds exclusive starts on entry; inclusive ENDS on exit
// (cur[d] == off[d+1]); gather derives start = (d ? cur[d-1] : 0).
__global__ void fill_both(const int* __restrict__ adj1,
                          const int* __restrict__ adj2,
                          int* __restrict__ cur1, int* __restrict__ cur2,
                          int* __restrict__ csr1, int* __restrict__ csr2,
                          const int* __restrict__ flagIdx, int nE1, int nE2) {
  int t = blockIdx.x * blockDim.x + threadIdx.x;
  int f = *flagIdx;
  if (t < nE1) {
    int s, d;
    if (f) {
      s = adj1[2 * t];
      d = adj1[2 * nE1 + 2 * t];
    } else {
      s = adj1[t];
      d = adj1[nE1 + t];
    }
    if (d < NJ) csr1[atomicAdd(&cur1[d], 1)] = s;
  } else if (t < nE1 + nE2) {
    int e = t - nE1;
    int s, d;
    if (f) {
      s = adj2[2 * e];
      d = adj2[2 * nE2 + 2 * e];
    } else {
      s = adj2[e];
      d = adj2[nE2 + e];
    }
    if (d < NI) csr2[atomicAdd(&cur2[d], 1)] = s;
  }
}

// Fused gather + dense, 32 rows/block.
// Gather: 8 teams x 32 lanes, 4 rows per team, lane owns 16 B; 8-deep unroll.
// Dense: thread owns 8 rows x 2 cols; per k-quad: 8 LDS broadcasts + 2
// coalesced W float4 + 64 FMA. A wave is uniform in row-group, so all As
// reads are bank-conflict-free broadcasts.
// LAYER==1: relu + dropout epilogue.
template <int LAYER>
__global__ __launch_bounds__(256) void dense_kernel(
    const float* __restrict__ xsrc, const int* __restrict__ csr,
    const int* __restrict__ offEnd, const float* __restrict__ xin,
    const float* __restrict__ WTp, const float* __restrict__ bias,
    float* __restrict__ out, int M) {
  __shared__ float As[32 * 256];  // 32 KB
  const int tid = threadIdx.x;
  const int rowBase = blockIdx.x * 32;

  // ---- gather phase ----
  {
    const int team = tid >> 5;      // 0..7
    const int l4 = (tid & 31) * 4;  // float4 slot within row
#pragma unroll
    for (int rr = 0; rr < 4; ++rr) {
      const int r = team * 4 + rr;
      int rg = rowBase + r;
      if (rg >= M) rg = M - 1;  // clamped read; stores guarded below
      const int end = offEnd[rg];
      const int start = (rg == 0) ? 0 : offEnd[rg - 1];
      float4 a0 = {0.f, 0.f, 0.f, 0.f}, a1 = a0, a2 = a0, a3 = a0;
      int e = start;
      for (; e + 7 < end; e += 8) {
        int s0 = csr[e], s1 = csr[e + 1], s2 = csr[e + 2], s3 = csr[e + 3];
        int s4 = csr[e + 4], s5 = csr[e + 5], s6 = csr[e + 6], s7 = csr[e + 7];
        float4 v0 = ld4(xsrc + (size_t)s0 * DD + l4);
        float4 v1 = ld4(xsrc + (size_t)s1 * DD + l4);
        float4 v2 = ld4(xsrc + (size_t)s2 * DD + l4);
        float4 v3 = ld4(xsrc + (size_t)s3 * DD + l4);
        float4 v4 = ld4(xsrc + (size_t)s4 * DD + l4);
        float4 v5 = ld4(xsrc + (size_t)s5 * DD + l4);
        float4 v6 = ld4(xsrc + (size_t)s6 * DD + l4);
        float4 v7 = ld4(xsrc + (size_t)s7 * DD + l4);
        a0.x += v0.x; a0.y += v0.y; a0.z += v0.z; a0.w += v0.w;
        a1.x += v1.x; a1.y += v1.y; a1.z += v1.z; a1.w += v1.w;
        a2.x += v2.x; a2.y += v2.y; a2.z += v2.z; a2.w += v2.w;
        a3.x += v3.x; a3.y += v3.y; a3.z += v3.z; a3.w += v3.w;
        a0.x += v4.x; a0.y += v4.y; a0.z += v4.z; a0.w += v4.w;
        a1.x += v5.x; a1.y += v5.y; a1.z += v5.z; a1.w += v5.w;
        a2.x += v6.x; a2.y += v6.y; a2.z += v6.z; a2.w += v6.w;
        a3.x += v7.x; a3.y += v7.y; a3.z += v7.z; a3.w += v7.w;
      }
      for (; e + 3 < end; e += 4) {
        int s0 = csr[e], s1 = csr[e + 1], s2 = csr[e + 2], s3 = csr[e + 3];
        float4 v0 = ld4(xsrc + (size_t)s0 * DD + l4);
        float4 v1 = ld4(xsrc + (size_t)s1 * DD + l4);
        float4 v2 = ld4(xsrc + (size_t)s2 * DD + l4);
        float4 v3 = ld4(xsrc + (size_t)s3 * DD + l4);
        a0.x += v0.x; a0.y += v0.y; a0.z += v0.z; a0.w += v0.w;
        a1.x += v1.x; a1.y += v1.y; a1.z += v1.z; a1.w += v1.w;
        a2.x += v2.x; a2.y += v2.y; a2.z += v2.z; a2.w += v2.w;
        a3.x += v3.x; a3.y += v3.y; a3.z += v3.z; a3.w += v3.w;
      }
      for (; e < end; ++e) {
        float4 v = ld4(xsrc + (size_t)csr[e] * DD + l4);
        a0.x += v.x; a0.y += v.y; a0.z += v.z; a0.w += v.w;
      }
      a0.x += a1.x + a2.x + a3.x;
      a0.y += a1.y + a2.y + a3.y;
      a0.z += a1.z + a2.z + a3.z;
      a0.w += a1.w + a2.w + a3.w;
      float rdeg = 1.0f / fmaxf((float)(end - start), 1.0f);
      a0.x *= rdeg; a0.y *= rdeg; a0.z *= rdeg; a0.w *= rdeg;
      *(float4*)(As + r * 256 + l4) = a0;
      *(float4*)(As + r * 256 + DD + l4) = ld4(xin + (size_t)rg * DD + l4);
    }
  }
  __syncthreads();

  // ---- dense phase: 8 rows x 2 cols per thread ----
  const int u = tid & 63;   // cols u, u+64
  const int g = tid >> 6;   // row group 0..3 (wave-uniform)
  const int r0 = g * 8;
  float acc[8][2];
#pragma unroll
  for (int r = 0; r < 8; ++r) acc[r][0] = acc[r][1] = 0.f;

#pragma unroll 8
  for (int k0 = 0; k0 < 256; k0 += 4) {
    const float* wbase = WTp + (k0 >> 2) * (DD * 4);
    float4 w0 = ld4(wbase + u * 4);
    float4 w1 = ld4(wbase + (u + 64) * 4);
#pragma unroll
    for (int r = 0; r < 8; ++r) {
      float4 a = *(const float4*)(As + (r0 + r) * 256 + k0);
      acc[r][0] += a.x * w0.x + a.y * w0.y + a.z * w0.z + a.w * w0.w;
      acc[r][1] += a.x * w1.x + a.y * w1.y + a.z * w1.z + a.w * w1.w;
    }
  }

  const float b0 = bias[u];
  const float b1 = bias[u + 64];
#pragma unroll
  for (int r = 0; r < 8; ++r) {
    int rg = rowBase + r0 + r;
    if (rg >= M) continue;
    float v0 = acc[r][0] + b0;
    float v1 = acc[r][1] + b1;
    if (LAYER == 1) {
      v0 = fmaxf(v0, 0.0f);
      v1 = fmaxf(v1, 0.0f);
      uint32_t fbase = (uint32_t)rg * DD;
      v0 = dropout_keep(fbase + (uint32_t)u) ? v0 * 2.0f : 0.0f;
      v1 = dropout_keep(fbase + (uint32_t)u + 64u) ? v1 * 2.0f : 0.0f;
    }
    out[(size_t)rg * DD + u] = v0;
    out[(size_t)rg * DD + u + 64] = v1;
  }
}

extern "C" void kernel_launch(void* const* d_in, const int* in_sizes, int n_in,
                              void* d_out, int out_size, void* d_ws, size_t ws_size,
                              hipStream_t stream) {
  const float* feat = (const float*)d_in[0];   // fp32 (R4 NaN proof)
  const int* t_adj = (const int*)d_in[1];
  const int* n_adj = (const int*)d_in[2];
  const float* W1l = (const float*)d_in[5];
  const float* b1 = (const float*)d_in[6];
  const float* W1r = (const float*)d_in[7];
  const float* W2l = (const float*)d_in[8];
  const float* b2 = (const float*)d_in[9];
  const float* W2r = (const float*)d_in[10];

  const int E1 = in_sizes[1] / 2;
  const int E2 = in_sizes[2] / 2;

  // Workspace ~16 MB.
  float* ws = (float*)d_ws;
  float* x1 = ws;                       // 3,200,000 f
  float* WT1 = x1 + 3200000;            //    32,768 f
  float* WT2 = WT1 + 32768;             //    32,768 f
  int* off1 = (int*)(WT2 + 32768);      //    NJ
  int* off2 = off1 + NJ;                //    NI
  int* csr1 = off2 + NI;                //    E1 (max)
  int* csr2 = csr1 + E1;                //    E2 (max)
  int* flagIdx = csr2 + E2;             //    1

  const int nZero = NJ + NI;
  const int zeroBlocks = (nZero + 255) / 256;
  setup_kernel<<<257 + zeroBlocks, 256, 0, stream>>>(
      W1l, W1r, WT1, W2l, W2r, WT2, t_adj, flagIdx, off1, nZero);

  const int nTot = E1 + E2;
  hist_both<<<(nTot + 255) / 256, 256, 0, stream>>>(t_adj, n_adj, off1, off2,
                                                    flagIdx, E1, E2);
  scan2<<<2, 256, 0, stream>>>(off1, NJ, off2, NI);
  fill_both<<<(nTot + 255) / 256, 256, 0, stream>>>(
      t_adj, n_adj, off1, off2, csr1, csr2, flagIdx, E1, E2);

  dense_kernel<1><<<(NJ + 31) / 32, 256, 0, stream>>>(feat, csr1, off1, feat,
                                                      WT1, b1, x1, NJ);
  dense_kernel<2><<<(NI + 31) / 32, 256, 0, stream>>>(x1, csr2, off2, x1, WT2,
                                                      b2, (float*)d_out, NI);
}

// Round 4
// 295.441 us; speedup vs baseline: 11.1219x; 1.0017x over previous
//
#include <hip/hip_runtime.h>
#include <stdint.h>

#define DD 128
#define NJ 25000
#define NI 12500

__device__ __forceinline__ uint32_t rotl32(uint32_t v, int n) {
  return (v << n) | (v >> (32 - n));
}

// JAX threefry2x32, key=(0,1). Core KAT-verified vs Random123.
__device__ __forceinline__ void threefry_0_1(uint32_t& x0, uint32_t& x1) {
  const uint32_t ks0 = 0u, ks1 = 1u, ks2 = 0x1BD11BDBu;
  x0 += ks0; x1 += ks1;
#define TF_R4(a,b,c,d)                                  \
  x0 += x1; x1 = rotl32(x1,(a)); x1 ^= x0;              \
  x0 += x1; x1 = rotl32(x1,(b)); x1 ^= x0;              \
  x0 += x1; x1 = rotl32(x1,(c)); x1 ^= x0;              \
  x0 += x1; x1 = rotl32(x1,(d)); x1 ^= x0;
  TF_R4(13,15,26,6)   x0 += ks1; x1 += ks2 + 1u;
  TF_R4(17,29,16,24)  x0 += ks2; x1 += ks0 + 2u;
  TF_R4(13,15,26,6)   x0 += ks0; x1 += ks1 + 3u;
  TF_R4(17,29,16,24)  x0 += ks1; x1 += ks2 + 4u;
  TF_R4(13,15,26,6)   x0 += ks2; x1 += ks0 + 5u;
#undef TF_R4
}

// MASK IDENTIFIED (R16 sweep, unique match v5): partitionable threefry,
// ctr = (0, f), 32-bit draw = o0 ^ o1; keep <=> bit31(o0 ^ o1) == 0.
__device__ __forceinline__ bool dropout_keep(uint32_t f) {
  uint32_t x0 = 0u, x1 = f;
  threefry_0_1(x0, x1);
  return ((x0 ^ x1) >> 31) == 0u;
}

__device__ __forceinline__ float4 ld4(const float* p) {
  return *(const float4*)p;
}

// Fused setup (one dispatch):
//   blocks 0..255   : weight prep for BOTH layers
//   block  256      : int64-as-int32-pairs detect (odd words zero)
//   blocks 257..    : zero off1/off2 histogram arrays
// WTp[(k>>2)*512 + c*4 + (k&3)] = Wcat[c][k]; Wcat = [W_l | W_r] along k.
__global__ void setup_kernel(const float* __restrict__ Wl1,
                             const float* __restrict__ Wr1,
                             float* __restrict__ WT1,
                             const float* __restrict__ Wl2,
                             const float* __restrict__ Wr2,
                             float* __restrict__ WT2,
                             const int* __restrict__ adjw,
                             int* __restrict__ flag,
                             int* __restrict__ offZero, int nZero) {
  const int b = blockIdx.x;
  if (b < 256) {
    int t = b * 256 + threadIdx.x;  // 0..65535 covers both weight sets
    int which = t >= DD * 256;
    int idx = which ? t - DD * 256 : t;
    const float* Wl = which ? Wl2 : Wl1;
    const float* Wr = which ? Wr2 : Wr1;
    float* WTp = which ? WT2 : WT1;
    int c = idx >> 8;
    int k = idx & 255;
    float v = (k < DD) ? Wl[c * DD + k] : Wr[c * DD + (k - DD)];
    WTp[(k >> 2) * (DD * 4) + c * 4 + (k & 3)] = v;
  } else if (b == 256) {
    if (threadIdx.x == 0) {
      int is64 = 1;
      for (int e = 0; e < 16; ++e)
        if (adjw[2 * e + 1] != 0) is64 = 0;
      *flag = is64;
    }
  } else {
    int i = (b - 257) * 256 + threadIdx.x;
    if (i < nZero) offZero[i] = 0;
  }
}

// ---- CSR build (both graphs): hist -> scan -> fill ----

__global__ void hist_both(const int* __restrict__ adj1,
                          const int* __restrict__ adj2,
                          int* __restrict__ cnt1, int* __restrict__ cnt2,
                          const int* __restrict__ flagIdx, int nE1, int nE2) {
  int t = blockIdx.x * blockDim.x + threadIdx.x;
  int f = *flagIdx;
  if (t < nE1) {
    int d;
    if (f) {
      int2 p = *(const int2*)(adj1 + 2 * nE1 + 2 * t);  // 8B-aligned
      d = p.x;
    } else {
      d = adj1[nE1 + t];
    }
    if (d < NJ) atomicAdd(&cnt1[d], 1);
  } else if (t < nE1 + nE2) {
    int e = t - nE1;
    int d;
    if (f) {
      int2 p = *(const int2*)(adj2 + 2 * nE2 + 2 * e);
      d = p.x;
    } else {
      d = adj2[nE2 + e];
    }
    if (d < NI) atomicAdd(&cnt2[d], 1);
  }
}

// In-place exclusive scan; block 0 -> (a1,n1), block 1 -> (a2,n2).
__global__ void scan2(int* __restrict__ a1, int n1, int* __restrict__ a2,
                      int n2) {
  __shared__ int part[1024];
  int* a = blockIdx.x ? a2 : a1;
  const int n = blockIdx.x ? n2 : n1;
  const int t = threadIdx.x;
  const int per = (n + 1023) / 1024;
  int lo = t * per;
  int hi = lo + per;
  if (hi > n) hi = n;
  int sum = 0;
  for (int i = lo; i < hi; ++i) sum += a[i];
  part[t] = sum;
  __syncthreads();
  for (int ofs = 1; ofs < 1024; ofs <<= 1) {
    int v = (t >= ofs) ? part[t - ofs] : 0;
    __syncthreads();
    part[t] += v;
    __syncthreads();
  }
  int run = (t == 0) ? 0 : part[t - 1];
  for (int i = lo; i < hi; ++i) {
    int v = a[i];
    a[i] = run;
    run += v;
  }
}

// fill: cur[] holds exclusive starts on entry; inclusive ENDS on exit
// (cur[d] == off[d+1]); gather derives start = (d ? cur[d-1] : 0).
__global__ void fill_both(const int* __restrict__ adj1,
                          const int* __restrict__ adj2,
                          int* __restrict__ cur1, int* __restrict__ cur2,
                          int* __restrict__ csr1, int* __restrict__ csr2,
                          const int* __restrict__ flagIdx, int nE1, int nE2) {
  int t = blockIdx.x * blockDim.x + threadIdx.x;
  int f = *flagIdx;
  if (t < nE1) {
    int s, d;
    if (f) {
      int2 ps = *(const int2*)(adj1 + 2 * t);
      int2 pd = *(const int2*)(adj1 + 2 * nE1 + 2 * t);
      s = ps.x;
      d = pd.x;
    } else {
      s = adj1[t];
      d = adj1[nE1 + t];
    }
    if (d < NJ) csr1[atomicAdd(&cur1[d], 1)] = s;
  } else if (t < nE1 + nE2) {
    int e = t - nE1;
    int s, d;
    if (f) {
      int2 ps = *(const int2*)(adj2 + 2 * e);
      int2 pd = *(const int2*)(adj2 + 2 * nE2 + 2 * e);
      s = ps.x;
      d = pd.x;
    } else {
      s = adj2[e];
      d = adj2[nE2 + e];
    }
    if (d < NI) csr2[atomicAdd(&cur2[d], 1)] = s;
  }
}

// Fused gather + dense, 16 rows/block (occupancy-tuned: LDS 16 KB -> up to
// 10 blocks/CU; grid 2x vs 32-row variant for gather latency hiding).
// Gather: 8 teams x 32 lanes, 2 rows per team, lane owns 16 B; 8-deep unroll.
// Dense: thread owns 4 rows x 2 cols; As reads are wave-uniform broadcasts.
// LAYER==1: relu + dropout epilogue.
template <int LAYER>
__global__ __launch_bounds__(256) void dense_kernel(
    const float* __restrict__ xsrc, const int* __restrict__ csr,
    const int* __restrict__ offEnd, const float* __restrict__ xin,
    const float* __restrict__ WTp, const float* __restrict__ bias,
    float* __restrict__ out, int M) {
  __shared__ float As[16 * 256];  // 16 KB
  const int tid = threadIdx.x;
  const int rowBase = blockIdx.x * 16;

  // ---- gather phase ----
  {
    const int team = tid >> 5;      // 0..7
    const int l4 = (tid & 31) * 4;  // float4 slot within row
#pragma unroll
    for (int rr = 0; rr < 2; ++rr) {
      const int r = team * 2 + rr;
      int rg = rowBase + r;
      if (rg >= M) rg = M - 1;  // clamped read; stores guarded below
      const int end = offEnd[rg];
      const int start = (rg == 0) ? 0 : offEnd[rg - 1];
      float4 a0 = {0.f, 0.f, 0.f, 0.f}, a1 = a0, a2 = a0, a3 = a0;
      int e = start;
      for (; e + 7 < end; e += 8) {
        int s0 = csr[e], s1 = csr[e + 1], s2 = csr[e + 2], s3 = csr[e + 3];
        int s4 = csr[e + 4], s5 = csr[e + 5], s6 = csr[e + 6], s7 = csr[e + 7];
        float4 v0 = ld4(xsrc + (size_t)s0 * DD + l4);
        float4 v1 = ld4(xsrc + (size_t)s1 * DD + l4);
        float4 v2 = ld4(xsrc + (size_t)s2 * DD + l4);
        float4 v3 = ld4(xsrc + (size_t)s3 * DD + l4);
        float4 v4 = ld4(xsrc + (size_t)s4 * DD + l4);
        float4 v5 = ld4(xsrc + (size_t)s5 * DD + l4);
        float4 v6 = ld4(xsrc + (size_t)s6 * DD + l4);
        float4 v7 = ld4(xsrc + (size_t)s7 * DD + l4);
        a0.x += v0.x; a0.y += v0.y; a0.z += v0.z; a0.w += v0.w;
        a1.x += v1.x; a1.y += v1.y; a1.z += v1.z; a1.w += v1.w;
        a2.x += v2.x; a2.y += v2.y; a2.z += v2.z; a2.w += v2.w;
        a3.x += v3.x; a3.y += v3.y; a3.z += v3.z; a3.w += v3.w;
        a0.x += v4.x; a0.y += v4.y; a0.z += v4.z; a0.w += v4.w;
        a1.x += v5.x; a1.y += v5.y; a1.z += v5.z; a1.w += v5.w;
        a2.x += v6.x; a2.y += v6.y; a2.z += v6.z; a2.w += v6.w;
        a3.x += v7.x; a3.y += v7.y; a3.z += v7.z; a3.w += v7.w;
      }
      for (; e + 3 < end; e += 4) {
        int s0 = csr[e], s1 = csr[e + 1], s2 = csr[e + 2], s3 = csr[e + 3];
        float4 v0 = ld4(xsrc + (size_t)s0 * DD + l4);
        float4 v1 = ld4(xsrc + (size_t)s1 * DD + l4);
        float4 v2 = ld4(xsrc + (size_t)s2 * DD + l4);
        float4 v3 = ld4(xsrc + (size_t)s3 * DD + l4);
        a0.x += v0.x; a0.y += v0.y; a0.z += v0.z; a0.w += v0.w;
        a1.x += v1.x; a1.y += v1.y; a1.z += v1.z; a1.w += v1.w;
        a2.x += v2.x; a2.y += v2.y; a2.z += v2.z; a2.w += v2.w;
        a3.x += v3.x; a3.y += v3.y; a3.z += v3.z; a3.w += v3.w;
      }
      for (; e < end; ++e) {
        float4 v = ld4(xsrc + (size_t)csr[e] * DD + l4);
        a0.x += v.x; a0.y += v.y; a0.z += v.z; a0.w += v.w;
      }
      a0.x += a1.x + a2.x + a3.x;
      a0.y += a1.y + a2.y + a3.y;
      a0.z += a1.z + a2.z + a3.z;
      a0.w += a1.w + a2.w + a3.w;
      float rdeg = 1.0f / fmaxf((float)(end - start), 1.0f);
      a0.x *= rdeg; a0.y *= rdeg; a0.z *= rdeg; a0.w *= rdeg;
      *(float4*)(As + r * 256 + l4) = a0;
      *(float4*)(As + r * 256 + DD + l4) = ld4(xin + (size_t)rg * DD + l4);
    }
  }
  __syncthreads();

  // ---- dense phase: 4 rows x 2 cols per thread ----
  const int u = tid & 63;   // cols u, u+64
  const int g = tid >> 6;   // row group 0..3 (wave-uniform)
  const int r0 = g * 4;
  float acc[4][2];
#pragma unroll
  for (int r = 0; r < 4; ++r) acc[r][0] = acc[r][1] = 0.f;

#pragma unroll 8
  for (int k0 = 0; k0 < 256; k0 += 4) {
    const float* wbase = WTp + (k0 >> 2) * (DD * 4);
    float4 w0 = ld4(wbase + u * 4);
    float4 w1 = ld4(wbase + (u + 64) * 4);
#pragma unroll
    for (int r = 0; r < 4; ++r) {
      float4 a = *(const float4*)(As + (r0 + r) * 256 + k0);
      acc[r][0] += a.x * w0.x + a.y * w0.y + a.z * w0.z + a.w * w0.w;
      acc[r][1] += a.x * w1.x + a.y * w1.y + a.z * w1.z + a.w * w1.w;
    }
  }

  const float b0 = bias[u];
  const float b1 = bias[u + 64];
#pragma unroll
  for (int r = 0; r < 4; ++r) {
    int rg = rowBase + r0 + r;
    if (rg >= M) continue;
    float v0 = acc[r][0] + b0;
    float v1 = acc[r][1] + b1;
    if (LAYER == 1) {
      v0 = fmaxf(v0, 0.0f);
      v1 = fmaxf(v1, 0.0f);
      uint32_t fbase = (uint32_t)rg * DD;
      v0 = dropout_keep(fbase + (uint32_t)u) ? v0 * 2.0f : 0.0f;
      v1 = dropout_keep(fbase + (uint32_t)u + 64u) ? v1 * 2.0f : 0.0f;
    }
    out[(size_t)rg * DD + u] = v0;
    out[(size_t)rg * DD + u + 64] = v1;
  }
}

extern "C" void kernel_launch(void* const* d_in, const int* in_sizes, int n_in,
                              void* d_out, int out_size, void* d_ws, size_t ws_size,
                              hipStream_t stream) {
  const float* feat = (const float*)d_in[0];   // fp32 (R4 NaN proof)
  const int* t_adj = (const int*)d_in[1];
  const int* n_adj = (const int*)d_in[2];
  const float* W1l = (const float*)d_in[5];
  const float* b1 = (const float*)d_in[6];
  const float* W1r = (const float*)d_in[7];
  const float* W2l = (const float*)d_in[8];
  const float* b2 = (const float*)d_in[9];
  const float* W2r = (const float*)d_in[10];

  const int E1 = in_sizes[1] / 2;
  const int E2 = in_sizes[2] / 2;

  // Workspace ~16 MB.
  float* ws = (float*)d_ws;
  float* x1 = ws;                       // 3,200,000 f
  float* WT1 = x1 + 3200000;            //    32,768 f
  float* WT2 = WT1 + 32768;             //    32,768 f
  int* off1 = (int*)(WT2 + 32768);      //    NJ
  int* off2 = off1 + NJ;                //    NI
  int* csr1 = off2 + NI;                //    E1 (max)
  int* csr2 = csr1 + E1;                //    E2 (max)
  int* flagIdx = csr2 + E2;             //    1

  const int nZero = NJ + NI;
  const int zeroBlocks = (nZero + 255) / 256;
  setup_kernel<<<257 + zeroBlocks, 256, 0, stream>>>(
      W1l, W1r, WT1, W2l, W2r, WT2, t_adj, flagIdx, off1, nZero);

  const int nTot = E1 + E2;
  hist_both<<<(nTot + 255) / 256, 256, 0, stream>>>(t_adj, n_adj, off1, off2,
                                                    flagIdx, E1, E2);
  scan2<<<2, 1024, 0, stream>>>(off1, NJ, off2, NI);
  fill_both<<<(nTot + 255) / 256, 256, 0, stream>>>(
      t_adj, n_adj, off1, off2, csr1, csr2, flagIdx, E1, E2);

  dense_kernel<1><<<(NJ + 15) / 16, 256, 0, stream>>>(feat, csr1, off1, feat,
                                                      WT1, b1, x1, NJ);
  dense_kernel<2><<<(NI + 15) / 16, 256, 0, stream>>>(x1, csr2, off2, x1, WT2,
                                                      b2, (float*)d_out, NI);
}